// Round 8
// baseline (524.243 us; speedup 1.0000x reference)
//
#include <hip/hip_runtime.h>
#include <hip/hip_bf16.h>

typedef __bf16 bf16x8 __attribute__((ext_vector_type(8)));
typedef float f32x4 __attribute__((ext_vector_type(4)));

#define MFMA16(A, B, C) __builtin_amdgcn_mfma_f32_16x16x32_bf16(A, B, C, 0, 0, 0)

// async global->LDS, 16B per lane. LDS dest = wave-uniform base + lane*16.
#define GLDS(gp, lp)                                                              \
    __builtin_amdgcn_global_load_lds(                                             \
        (const __attribute__((address_space(1))) void*)(gp),                      \
        (__attribute__((address_space(3))) void*)(lp), 16, 0, 0)

// ---------------------------------------------------------------------------
// Fused weight transpose + fp32->bf16 for all 7 weights: W[K,N] -> Wt[N,K]
// ---------------------------------------------------------------------------
struct PtrW { const float* p[7]; };
__global__ __launch_bounds__(256) void wt_transpose(PtrW W, __hip_bfloat16* __restrict__ Wt) {
    const float* __restrict__ src = W.p[blockIdx.z];
    __hip_bfloat16* __restrict__ dst = Wt + ((size_t)blockIdx.z << 20);
    __shared__ float tile[32][33];
    const int bn = blockIdx.x * 32;
    const int bk = blockIdx.y * 32;
    const int tx = threadIdx.x, ty = threadIdx.y;
#pragma unroll
    for (int i = 0; i < 4; i++) {
        tile[ty + i * 8][tx] = src[(size_t)(bk + ty + i * 8) * 1024 + bn + tx];
    }
    __syncthreads();
#pragma unroll
    for (int i = 0; i < 4; i++) {
        dst[(size_t)(bn + ty + i * 8) * 1024 + bk + tx] =
            __float2bfloat16(tile[tx][ty + i * 8]);
    }
}

struct PtrC { const float* s[2]; __hip_bfloat16* d[2]; };
__global__ __launch_bounds__(256) void to_bf16(PtrC c) {
    const int z = blockIdx.y;
    const int i = (blockIdx.x * 256 + threadIdx.x) * 4;
    const float4 v = *(const float4*)(c.s[z] + i);
    __align__(8) __hip_bfloat16 t[4] = {__float2bfloat16(v.x), __float2bfloat16(v.y),
                                        __float2bfloat16(v.z), __float2bfloat16(v.w)};
    *(uint2*)(c.d[z] + i) = *(const uint2*)t;
}

struct Ptr2 { const float* p[2]; };
__global__ __launch_bounds__(256) void bias_concat(Ptr2 srcs, float* __restrict__ dst) {
    const int i = threadIdx.x * 4;
    *(float4*)(dst + blockIdx.x * 1024 + i) = *(const float4*)(srcs.p[blockIdx.x] + i);
}

// ---------------------------------------------------------------------------
// Multi-job GEMM. All jobs: K=1024, A row-major stride 1024, 128x128 tiles,
// 4 waves 2x2, BK=32 double-buffered GLDS, 1 barrier/step.
// Job types: N>0  -> C[token][N] = A @ B^T + bias (per-col), optional qscale.
//            N==0 -> V^T planes: C^T per batch, A=W^T[feat][k], B=X tokens of
//                    batch bb (row stride 8192); out Vt[(bb,h)][d][t].
// ---------------------------------------------------------------------------
struct Job {
    const __hip_bfloat16* A;
    const __hip_bfloat16* B;
    const float* bias;
    __hip_bfloat16* out;
    int bstride;   // B row stride (elements)
    int N;         // out cols (rowmajor) or 0 (vt)
    int nblocks;
    int gx;        // blocks along M
    float qscale;
    int qcols;
};
struct Jobs { Job j[4]; int njobs; };

__global__ __launch_bounds__(256) void gemm_multi(Jobs J) {
    int bid = blockIdx.x;
    int ji = 0;
    while (ji < J.njobs - 1 && bid >= J.j[ji].nblocks) {
        bid -= J.j[ji].nblocks;
        ji++;
    }
    const Job job = J.j[ji];
    int bx, by, bb;
    if (job.N) {
        bx = bid % job.gx;
        by = bid / job.gx;
        bb = 0;
    } else {
        bx = bid & 7;
        by = (bid >> 3) & 7;
        bb = bid >> 6;
    }
    __shared__ __align__(16) __hip_bfloat16 As[2][128 * 32];
    __shared__ __align__(16) __hip_bfloat16 Bs[2][128 * 32];
    const int tid = threadIdx.x;
    const int wave = tid >> 6, lane = tid & 63;
    const int quad = lane >> 4, l16 = lane & 15;
    const int m0 = bx * 128, n0 = by * 128;
    const int wm = (wave & 1) * 64, wn = (wave >> 1) * 64;
    const int srow = lane >> 2;
    const int lc = (lane & 3) ^ ((lane >> 3) & 3);
    const __hip_bfloat16* Bbase = job.B + (job.N ? 0 : bb * 1024);
    const __hip_bfloat16* ap[2];
    const __hip_bfloat16* bp[2];
    int loff[2];
#pragma unroll
    for (int u = 0; u < 2; u++) {
        const int g = wave * 2 + u;
        const int row = g * 16 + srow;
        ap[u] = job.A + (size_t)(m0 + row) * 1024 + lc * 8;
        bp[u] = Bbase + (size_t)(n0 + row) * job.bstride + lc * 8;
        loff[u] = g * 512;
    }
    const int pch = quad ^ ((l16 >> 1) & 3);
    f32x4 acc[4][4] = {};
#pragma unroll
    for (int u = 0; u < 2; u++) {
        GLDS(ap[u], &As[0][loff[u]]);
        GLDS(bp[u], &Bs[0][loff[u]]);
    }
    int sel = 0;
    for (int k0 = 0; k0 < 1024; k0 += 32) {
        __syncthreads();
        if (k0 + 32 < 1024) {
#pragma unroll
            for (int u = 0; u < 2; u++) {
                GLDS(ap[u] + k0 + 32, &As[sel ^ 1][loff[u]]);
                GLDS(bp[u] + k0 + 32, &Bs[sel ^ 1][loff[u]]);
            }
        }
        bf16x8 af[4], bfr[4];
#pragma unroll
        for (int i = 0; i < 4; i++) {
            af[i] = *(const bf16x8*)(&As[sel][(wm + i * 16 + l16) * 32 + pch * 8]);
            bfr[i] = *(const bf16x8*)(&Bs[sel][(wn + i * 16 + l16) * 32 + pch * 8]);
        }
#pragma unroll
        for (int i = 0; i < 4; i++)
#pragma unroll
            for (int j = 0; j < 4; j++)
                acc[i][j] = MFMA16(af[i], bfr[j], acc[i][j]);
        sel ^= 1;
    }
    if (job.N) {
        // token-major epilogue: C row = quad*4+reg, col = l16
#pragma unroll
        for (int i = 0; i < 4; i++) {
#pragma unroll
            for (int j = 0; j < 4; j++) {
                const int mr = m0 + wm + i * 16 + quad * 4;
                const int nc = n0 + wn + j * 16 + l16;
                const float sc = (nc < job.qcols) ? job.qscale : 1.0f;
                const float bv = job.bias[nc];
#pragma unroll
                for (int r = 0; r < 4; r++) {
                    const float v = (acc[i][j][r] + bv) * sc;
                    job.out[(size_t)(mr + r) * job.N + nc] = __float2bfloat16(v);
                }
            }
        }
    } else {
        // V^T plane epilogue: feature d = mr+r, token col nc
#pragma unroll
        for (int i = 0; i < 4; i++) {
            const int mr = m0 + wm + i * 16 + quad * 4;
            float bias_r[4];
#pragma unroll
            for (int r = 0; r < 4; r++) bias_r[r] = job.bias[mr + r];
#pragma unroll
            for (int j = 0; j < 4; j++) {
                const int nc = n0 + wn + j * 16 + l16;
#pragma unroll
                for (int r = 0; r < 4; r++) {
                    const int d = mr + r;
                    const size_t idx = ((size_t)bb << 20) + ((size_t)(d >> 6) << 16) +
                                       (size_t)(d & 63) * 1024 + nc;
                    job.out[idx] = __float2bfloat16(acc[i][j][r] + bias_r[r]);
                }
            }
        }
    }
}

// ---------------------------------------------------------------------------
// Flash attention: LDS-staged K/V (GLDS, double-buffered, 1 barrier/tile),
// 128 q-rows per block (2 groups/wave share each K/V fragment), XCD swizzle,
// no-max softmax (scores bounded; softmax shift-invariant).
//   S^T = K @ Q^T (q = l16 per lane), O^T = V^T @ P^T, sum via ones-MFMA.
// grid: 1024 blocks = 8 XCD-slots x 16 bh x 8 q-tiles(128).
// ---------------------------------------------------------------------------
__global__ __launch_bounds__(256) void attn_kernel(
    const __hip_bfloat16* __restrict__ Qp, const __hip_bfloat16* __restrict__ Kp,
    const __hip_bfloat16* __restrict__ Vt, __hip_bfloat16* __restrict__ Ob,
    int T, int qRS, int kRS, int causal) {
    __shared__ __align__(16) __hip_bfloat16 Ks[2][64 * 64];
    __shared__ __align__(16) __hip_bfloat16 Vs[2][64 * 64];
    __shared__ __align__(16) __hip_bfloat16 Ps[4][16 * 64];
    const int tid = threadIdx.x, wave = tid >> 6, lane = tid & 63;
    const int quad = lane >> 4, l16 = lane & 15;
    const int gid = blockIdx.x;
    const int bh = (gid & 7) * 16 + ((gid >> 3) & 15);
    const int qt = gid >> 7;
    const int b = bh & 7, h = bh >> 3;
    const int q0 = qt * 128;
    const int qstride = 8 * qRS, kstride = 8 * kRS;
    const int sw = l16 & 7;

    const int qg0 = q0 + wave * 16;
    const int qg1 = qg0 + 64;
    const int myq0 = qg0 + l16, myq1 = qg1 + l16;
    const __hip_bfloat16* qbase = Qp + (size_t)b * qRS + h * 64;
    const bf16x8 qf00 = *(const bf16x8*)(qbase + (size_t)myq0 * qstride + quad * 8);
    const bf16x8 qf01 = *(const bf16x8*)(qbase + (size_t)myq0 * qstride + 32 + quad * 8);
    const bf16x8 qf10 = *(const bf16x8*)(qbase + (size_t)myq1 * qstride + quad * 8);
    const bf16x8 qf11 = *(const bf16x8*)(qbase + (size_t)myq1 * qstride + 32 + quad * 8);
    bf16x8 onesf;
#pragma unroll
    for (int i = 0; i < 8; i++) onesf[i] = (__bf16)1.0f;

    const int jk = wave * 2;
    const int lrow = lane >> 3;
    const int lch = (lane & 7) ^ (lrow & 7);
    const __hip_bfloat16* kp0 =
        Kp + (size_t)b * kRS + h * 64 + (size_t)(jk * 8 + lrow) * kstride + lch * 8;
    const __hip_bfloat16* kp1 = kp0 + (size_t)8 * kstride;
    const __hip_bfloat16* vp0 =
        Vt + ((size_t)(b * 16 + h) << 16) + (size_t)(jk * 8 + lrow) * 1024 + lch * 8;
    const __hip_bfloat16* vp1 = vp0 + 8 * 1024;
    const size_t kinc = (size_t)64 * kstride;

    f32x4 o0[4] = {}, o1[4] = {};
    f32x4 ol0 = {}, ol1 = {};
    bf16x8 pf00, pf01, pf10, pf11;

    auto softmax = [&](f32x4* s, f32x4& ol, bf16x8& pf0, bf16x8& pf1, int qg, int myq,
                       int k0) {
        const bool nm = causal && (k0 + 63 > qg);
        if (nm) {
#pragma unroll
            for (int n = 0; n < 4; n++)
#pragma unroll
                for (int r = 0; r < 4; r++)
                    if (k0 + n * 16 + quad * 4 + r > myq) s[n][r] = -1e30f;
        }
#pragma unroll
        for (int n = 0; n < 4; n++) {
            const float p0 = __builtin_amdgcn_exp2f(s[n][0]);
            const float p1 = __builtin_amdgcn_exp2f(s[n][1]);
            const float p2 = __builtin_amdgcn_exp2f(s[n][2]);
            const float p3 = __builtin_amdgcn_exp2f(s[n][3]);
            const __hip_bfloat162 pa = __float22bfloat162_rn(make_float2(p0, p1));
            const __hip_bfloat162 pb = __float22bfloat162_rn(make_float2(p2, p3));
            uint2 w;
            w.x = *(const unsigned int*)&pa;
            w.y = *(const unsigned int*)&pb;
            const int gcp = 2 * n + (quad >> 1);
            *(uint2*)(&Ps[wave][l16 * 64 + ((gcp ^ sw) << 3) + (quad & 1) * 4]) = w;
        }
        pf0 = *(const bf16x8*)(&Ps[wave][l16 * 64 + ((quad ^ sw) << 3)]);
        pf1 = *(const bf16x8*)(&Ps[wave][l16 * 64 + (((quad + 4) ^ sw) << 3)]);
        ol = MFMA16(onesf, pf0, ol);
        ol = MFMA16(onesf, pf1, ol);
    };

    const int kend = causal ? (q0 + 128) : T;
    GLDS(kp0, &Ks[0][jk * 512]);
    GLDS(kp1, &Ks[0][jk * 512 + 512]);
    GLDS(vp0, &Vs[0][jk * 512]);
    GLDS(vp1, &Vs[0][jk * 512 + 512]);
    const __hip_bfloat16* kn0 = kp0 + kinc;
    const __hip_bfloat16* kn1 = kp1 + kinc;
    const __hip_bfloat16* vn0 = vp0 + 64;
    const __hip_bfloat16* vn1 = vp1 + 64;
    int sel = 0;
    for (int k0 = 0; k0 < kend; k0 += 64) {
        __syncthreads();
        if (k0 + 64 < kend) {
            GLDS(kn0, &Ks[sel ^ 1][jk * 512]);
            GLDS(kn1, &Ks[sel ^ 1][jk * 512 + 512]);
            GLDS(vn0, &Vs[sel ^ 1][jk * 512]);
            GLDS(vn1, &Vs[sel ^ 1][jk * 512 + 512]);
            kn0 += kinc; kn1 += kinc; vn0 += 64; vn1 += 64;
        }
        const bool act0 = !causal || (k0 <= qg0 + 15);
        f32x4 s0[4] = {}, s1[4] = {};
        {
            bf16x8 kf[4];
#pragma unroll
            for (int n = 0; n < 4; n++)
                kf[n] = *(const bf16x8*)(&Ks[sel][(n * 16 + l16) * 64 +
                                                  ((quad ^ sw) << 3)]);
#pragma unroll
            for (int n = 0; n < 4; n++) {
                if (act0) s0[n] = MFMA16(kf[n], qf00, s0[n]);
                s1[n] = MFMA16(kf[n], qf10, s1[n]);
            }
#pragma unroll
            for (int n = 0; n < 4; n++)
                kf[n] = *(const bf16x8*)(&Ks[sel][(n * 16 + l16) * 64 +
                                                  (((quad + 4) ^ sw) << 3)]);
#pragma unroll
            for (int n = 0; n < 4; n++) {
                if (act0) s0[n] = MFMA16(kf[n], qf01, s0[n]);
                s1[n] = MFMA16(kf[n], qf11, s1[n]);
            }
        }
        if (act0) softmax(s0, ol0, pf00, pf01, qg0, myq0, k0);
        softmax(s1, ol1, pf10, pf11, qg1, myq1, k0);
#pragma unroll
        for (int mm = 0; mm < 4; mm++) {
            const int vrow = (mm * 16 + l16) * 64;
            const bf16x8 vf0 = *(const bf16x8*)(&Vs[sel][vrow + ((quad ^ sw) << 3)]);
            const bf16x8 vf1 = *(const bf16x8*)(&Vs[sel][vrow + (((quad + 4) ^ sw) << 3)]);
            if (act0) {
                o0[mm] = MFMA16(vf0, pf00, o0[mm]);
                o0[mm] = MFMA16(vf1, pf01, o0[mm]);
            }
            o1[mm] = MFMA16(vf0, pf10, o1[mm]);
            o1[mm] = MFMA16(vf1, pf11, o1[mm]);
        }
        sel ^= 1;
    }
    const float inv0 = 1.0f / ol0[0];
    const float inv1 = 1.0f / ol1[0];
    __hip_bfloat16* ob0 = Ob + (size_t)b * 1024 + h * 64 + (size_t)myq0 * 8192;
    __hip_bfloat16* ob1 = Ob + (size_t)b * 1024 + h * 64 + (size_t)myq1 * 8192;
#pragma unroll
    for (int mm = 0; mm < 4; mm++) {
        __align__(8) __hip_bfloat16 t0[4] = {
            __float2bfloat16(o0[mm][0] * inv0), __float2bfloat16(o0[mm][1] * inv0),
            __float2bfloat16(o0[mm][2] * inv0), __float2bfloat16(o0[mm][3] * inv0)};
        *(uint2*)(ob0 + mm * 16 + quad * 4) = *(const uint2*)t0;
        __align__(8) __hip_bfloat16 t1[4] = {
            __float2bfloat16(o1[mm][0] * inv1), __float2bfloat16(o1[mm][1] * inv1),
            __float2bfloat16(o1[mm][2] * inv1), __float2bfloat16(o1[mm][3] * inv1)};
        *(uint2*)(ob1 + mm * 16 + quad * 4) = *(const uint2*)t1;
    }
}

// ---------------------------------------------------------------------------
// Fused residual + LayerNorm over D=1024, one WAVE per row (no LDS/barrier).
// ---------------------------------------------------------------------------
__global__ __launch_bounds__(256) void ln_res_kernel(
    const __hip_bfloat16* __restrict__ a, const float* __restrict__ resf,
    const __hip_bfloat16* __restrict__ resb, const float* __restrict__ g,
    const float* __restrict__ be, float* __restrict__ outf,
    __hip_bfloat16* __restrict__ outb) {
    const int tid = threadIdx.x, wave = tid >> 6, lane = tid & 63;
    const int row = blockIdx.x * 4 + wave;
    const size_t base = (size_t)row * 1024;
    float x[16];
#pragma unroll
    for (int c = 0; c < 4; c++) {
        const int off = c * 256 + lane * 4;
        const uint2 ar = *(const uint2*)(a + base + off);
        const __hip_bfloat16* ah = (const __hip_bfloat16*)&ar;
        if (resf) {
            const float4 rv = *(const float4*)(resf + base + off);
            x[c * 4 + 0] = __bfloat162float(ah[0]) + rv.x;
            x[c * 4 + 1] = __bfloat162float(ah[1]) + rv.y;
            x[c * 4 + 2] = __bfloat162float(ah[2]) + rv.z;
            x[c * 4 + 3] = __bfloat162float(ah[3]) + rv.w;
        } else {
            const uint2 br = *(const uint2*)(resb + base + off);
            const __hip_bfloat16* bhp = (const __hip_bfloat16*)&br;
#pragma unroll
            for (int k = 0; k < 4; k++)
                x[c * 4 + k] = __bfloat162float(ah[k]) + __bfloat162float(bhp[k]);
        }
    }
    float s = 0.f, ss = 0.f;
#pragma unroll
    for (int k = 0; k < 16; k++) {
        s += x[k];
        ss += x[k] * x[k];
    }
#pragma unroll
    for (int w = 32; w >= 1; w >>= 1) {
        s += __shfl_xor(s, w);
        ss += __shfl_xor(ss, w);
    }
    const float mean = s * (1.f / 1024.f);
    const float inv = rsqrtf(ss * (1.f / 1024.f) - mean * mean + 1e-5f);
#pragma unroll
    for (int c = 0; c < 4; c++) {
        const int off = c * 256 + lane * 4;
        const float4 gg = *(const float4*)(g + off);
        const float4 bb = *(const float4*)(be + off);
        float y[4];
        y[0] = (x[c * 4 + 0] - mean) * inv * gg.x + bb.x;
        y[1] = (x[c * 4 + 1] - mean) * inv * gg.y + bb.y;
        y[2] = (x[c * 4 + 2] - mean) * inv * gg.z + bb.z;
        y[3] = (x[c * 4 + 3] - mean) * inv * gg.w + bb.w;
        if (outf) *(float4*)(outf + base + off) = make_float4(y[0], y[1], y[2], y[3]);
        if (outb) {
            __align__(8) __hip_bfloat16 t[4] = {
                __float2bfloat16(y[0]), __float2bfloat16(y[1]),
                __float2bfloat16(y[2]), __float2bfloat16(y[3])};
            *(uint2*)(outb + base + off) = *(const uint2*)t;
        }
    }
}

// ---------------------------------------------------------------------------
extern "C" void kernel_launch(void* const* d_in, const int* in_sizes, int n_in,
                              void* d_out, int out_size, void* d_ws, size_t ws_size,
                              hipStream_t stream) {
    const float* enc = (const float*)d_in[0];
    const float* dec = (const float*)d_in[1];
    const float* Wq1 = (const float*)d_in[2];
    const float* bq1 = (const float*)d_in[3];
    const float* Wk1 = (const float*)d_in[4];
    const float* bk1 = (const float*)d_in[5];
    const float* Wv1 = (const float*)d_in[6];
    const float* bv1 = (const float*)d_in[7];
    const float* Wq2 = (const float*)d_in[8];
    const float* bq2 = (const float*)d_in[9];
    const float* Wk2 = (const float*)d_in[10];
    const float* bk2 = (const float*)d_in[11];
    const float* Wv2 = (const float*)d_in[12];
    const float* bv2 = (const float*)d_in[13];
    const float* Wl = (const float*)d_in[14];
    const float* bl = (const float*)d_in[15];
    const float* g1 = (const float*)d_in[16];
    const float* be1 = (const float*)d_in[17];
    const float* g2 = (const float*)d_in[18];
    const float* be2 = (const float*)d_in[19];
    const float* g3 = (const float*)d_in[20];
    const float* be3 = (const float*)d_in[21];
    float* outp = (float*)d_out;

    char* p = (char*)d_ws;
    auto alloc = [&](size_t n) {
        char* r = p;
        p += (n + 255) & ~(size_t)255;
        return r;
    };
    const size_t MD = (size_t)8192 * 1024;
    __hip_bfloat16* enc_b = (__hip_bfloat16*)alloc(MD * 2);
    __hip_bfloat16* dec_b = (__hip_bfloat16*)alloc(MD * 2);
    __hip_bfloat16* Wt = (__hip_bfloat16*)alloc((size_t)7 * 1024 * 1024 * 2);
    float* bcat = (float*)alloc(2048 * sizeof(float));
    __hip_bfloat16* qk = (__hip_bfloat16*)alloc(MD * 2 * 2);  // QK1 [8192][2048]
    __hip_bfloat16* k2b = (__hip_bfloat16*)alloc(MD * 2);     // K2 [8192][1024]
    __hip_bfloat16* qb = (__hip_bfloat16*)alloc(MD * 2);      // Q2; reused as z
    __hip_bfloat16* attnb = (__hip_bfloat16*)alloc(MD * 2);   // attn outputs
    __hip_bfloat16* Vtb = (__hip_bfloat16*)alloc(MD * 2);     // V^T planes (attn1)
    __hip_bfloat16* Vtb2 = (__hip_bfloat16*)alloc(MD * 2);    // V^T planes (attn2)
    __hip_bfloat16* xb = dec_b;  // dec_b dead after mega-GEMM
    __hip_bfloat16* yb = enc_b;  // enc_b dead after mega-GEMM

    const float QSC = 0.18033688f;  // (1/sqrt(64)) * log2(e): softmax in exp2 domain

    PtrW wptrs = {{Wq1, Wk1, Wv1, Wq2, Wk2, Wv2, Wl}};
    wt_transpose<<<dim3(32, 32, 7), dim3(32, 8), 0, stream>>>(wptrs, Wt);
    PtrC cp = {{enc, dec}, {enc_b, dec_b}};
    to_bf16<<<dim3(8192, 2), 256, 0, stream>>>(cp);
    Ptr2 bp = {{bq1, bk1}};
    bias_concat<<<2, 256, 0, stream>>>(bp, bcat);

    // --- mega-GEMM: QK1 + VT1 + K2 + VT2 (all depend only on enc_b/dec_b) ---
    {
        Jobs J;
        // QK1: dec_b @ [Wq1;Wk1]^T -> qk [8192][2048], Q cols pre-scaled
        J.j[0] = {dec_b, Wt, bcat, qk, 1024, 2048, 64 * 16, 64, QSC, 1024};
        // VT1: Wv1^T plane GEMM from dec_b
        J.j[1] = {Wt + ((size_t)2 << 20), dec_b, bv1, Vtb, 8192, 0, 512, 8, 1.0f, 0};
        // K2: enc_b @ Wk2^T -> k2b
        J.j[2] = {enc_b, Wt + ((size_t)4 << 20), bk2, k2b, 1024, 1024, 64 * 8, 64, 1.0f, 0};
        // VT2: Wv2^T plane GEMM from enc_b
        J.j[3] = {Wt + ((size_t)5 << 20), enc_b, bv2, Vtb2, 8192, 0, 512, 8, 1.0f, 0};
        J.njobs = 4;
        gemm_multi<<<2560, 256, 0, stream>>>(J);
    }

    // --- self-attention ---
    attn_kernel<<<1024, 256, 0, stream>>>(qk, qk + 1024, Vtb, attnb,
                                          1024, 2048, 2048, 1);
    ln_res_kernel<<<2048, 256, 0, stream>>>(attnb, dec, nullptr, g1, be1, nullptr, xb);

    // --- cross-attention ---
    {
        Jobs J;
        J.j[0] = {xb, Wt + ((size_t)3 << 20), bq2, qb, 1024, 1024, 64 * 8, 64, QSC, 1024};
        J.njobs = 1;
        gemm_multi<<<512, 256, 0, stream>>>(J);
    }
    attn_kernel<<<1024, 256, 0, stream>>>(qb, k2b, Vtb2, attnb, 1024, 1024, 1024, 0);
    ln_res_kernel<<<2048, 256, 0, stream>>>(attnb, nullptr, xb, g2, be2, nullptr, yb);

    // --- position-wise linear ---
    {
        Jobs J;
        J.j[0] = {yb, Wt + ((size_t)6 << 20), bl, qb, 1024, 1024, 64 * 8, 64, 1.0f, 0};
        J.njobs = 1;
        gemm_multi<<<512, 256, 0, stream>>>(J);
    }
    ln_res_kernel<<<2048, 256, 0, stream>>>(qb, nullptr, yb, g3, be3, outp, nullptr);
}

// Round 9
// 499.408 us; speedup vs baseline: 1.0497x; 1.0497x over previous
//
#include <hip/hip_runtime.h>
#include <hip/hip_bf16.h>

typedef __bf16 bf16x8 __attribute__((ext_vector_type(8)));
typedef float f32x4 __attribute__((ext_vector_type(4)));

#define MFMA16(A, B, C) __builtin_amdgcn_mfma_f32_16x16x32_bf16(A, B, C, 0, 0, 0)

// async global->LDS, 16B per lane. LDS dest = wave-uniform base + lane*16.
#define GLDS(gp, lp)                                                              \
    __builtin_amdgcn_global_load_lds(                                             \
        (const __attribute__((address_space(1))) void*)(gp),                      \
        (__attribute__((address_space(3))) void*)(lp), 16, 0, 0)

// ---------------------------------------------------------------------------
// Fused weight transpose + fp32->bf16 for all 7 weights: W[K,N] -> Wt[N,K]
// ---------------------------------------------------------------------------
struct PtrW { const float* p[7]; };
__global__ __launch_bounds__(256) void wt_transpose(PtrW W, __hip_bfloat16* __restrict__ Wt) {
    const float* __restrict__ src = W.p[blockIdx.z];
    __hip_bfloat16* __restrict__ dst = Wt + ((size_t)blockIdx.z << 20);
    __shared__ float tile[32][33];
    const int bn = blockIdx.x * 32;
    const int bk = blockIdx.y * 32;
    const int tx = threadIdx.x, ty = threadIdx.y;
#pragma unroll
    for (int i = 0; i < 4; i++) {
        tile[ty + i * 8][tx] = src[(size_t)(bk + ty + i * 8) * 1024 + bn + tx];
    }
    __syncthreads();
#pragma unroll
    for (int i = 0; i < 4; i++) {
        dst[(size_t)(bn + ty + i * 8) * 1024 + bk + tx] =
            __float2bfloat16(tile[tx][ty + i * 8]);
    }
}

struct PtrC { const float* s[2]; __hip_bfloat16* d[2]; };
__global__ __launch_bounds__(256) void to_bf16(PtrC c) {
    const int z = blockIdx.y;
    const int i = (blockIdx.x * 256 + threadIdx.x) * 4;
    const float4 v = *(const float4*)(c.s[z] + i);
    __align__(8) __hip_bfloat16 t[4] = {__float2bfloat16(v.x), __float2bfloat16(v.y),
                                        __float2bfloat16(v.z), __float2bfloat16(v.w)};
    *(uint2*)(c.d[z] + i) = *(const uint2*)t;
}

struct Ptr2 { const float* p[2]; };
__global__ __launch_bounds__(256) void bias_concat(Ptr2 srcs, float* __restrict__ dst) {
    const int i = threadIdx.x * 4;
    *(float4*)(dst + blockIdx.x * 1024 + i) = *(const float4*)(srcs.p[blockIdx.x] + i);
}

// ---------------------------------------------------------------------------
// Multi-job GEMM. All jobs: K=1024, A row-major stride 1024, 128x128 tiles,
// 4 waves 2x2, BK=32 double-buffered GLDS, 1 barrier/step.
// Job types: N>0  -> C[token][N] = A @ B^T + bias (per-col), optional qscale.
//            N==0 -> V^T planes: C^T per batch, A=W^T[feat][k], B=X tokens of
//                    batch bb (row stride 8192); out Vt[(bb,h)][d][t].
// ---------------------------------------------------------------------------
struct Job {
    const __hip_bfloat16* A;
    const __hip_bfloat16* B;
    const float* bias;
    __hip_bfloat16* out;
    int bstride;   // B row stride (elements)
    int N;         // out cols (rowmajor) or 0 (vt)
    int nblocks;
    int gx;        // blocks along M
    float qscale;
    int qcols;
};
struct Jobs { Job j[3]; int njobs; };

__global__ __launch_bounds__(256) void gemm_multi(Jobs J) {
    int bid = blockIdx.x;
    int ji = 0;
    while (ji < J.njobs - 1 && bid >= J.j[ji].nblocks) {
        bid -= J.j[ji].nblocks;
        ji++;
    }
    const Job job = J.j[ji];
    int bx, by, bb;
    if (job.N) {
        bx = bid % job.gx;
        by = bid / job.gx;
        bb = 0;
    } else {
        bx = bid & 7;
        by = (bid >> 3) & 7;
        bb = bid >> 6;
    }
    __shared__ __align__(16) __hip_bfloat16 As[2][128 * 32];
    __shared__ __align__(16) __hip_bfloat16 Bs[2][128 * 32];
    const int tid = threadIdx.x;
    const int wave = tid >> 6, lane = tid & 63;
    const int quad = lane >> 4, l16 = lane & 15;
    const int m0 = bx * 128, n0 = by * 128;
    const int wm = (wave & 1) * 64, wn = (wave >> 1) * 64;
    const int srow = lane >> 2;
    const int lc = (lane & 3) ^ ((lane >> 3) & 3);
    const __hip_bfloat16* Bbase = job.B + (job.N ? 0 : bb * 1024);
    const __hip_bfloat16* ap[2];
    const __hip_bfloat16* bp[2];
    int loff[2];
#pragma unroll
    for (int u = 0; u < 2; u++) {
        const int g = wave * 2 + u;
        const int row = g * 16 + srow;
        ap[u] = job.A + (size_t)(m0 + row) * 1024 + lc * 8;
        bp[u] = Bbase + (size_t)(n0 + row) * job.bstride + lc * 8;
        loff[u] = g * 512;
    }
    const int pch = quad ^ ((l16 >> 1) & 3);
    f32x4 acc[4][4] = {};
#pragma unroll
    for (int u = 0; u < 2; u++) {
        GLDS(ap[u], &As[0][loff[u]]);
        GLDS(bp[u], &Bs[0][loff[u]]);
    }
    int sel = 0;
    for (int k0 = 0; k0 < 1024; k0 += 32) {
        __syncthreads();
        if (k0 + 32 < 1024) {
#pragma unroll
            for (int u = 0; u < 2; u++) {
                GLDS(ap[u] + k0 + 32, &As[sel ^ 1][loff[u]]);
                GLDS(bp[u] + k0 + 32, &Bs[sel ^ 1][loff[u]]);
            }
        }
        bf16x8 af[4], bfr[4];
#pragma unroll
        for (int i = 0; i < 4; i++) {
            af[i] = *(const bf16x8*)(&As[sel][(wm + i * 16 + l16) * 32 + pch * 8]);
            bfr[i] = *(const bf16x8*)(&Bs[sel][(wn + i * 16 + l16) * 32 + pch * 8]);
        }
#pragma unroll
        for (int i = 0; i < 4; i++)
#pragma unroll
            for (int j = 0; j < 4; j++)
                acc[i][j] = MFMA16(af[i], bfr[j], acc[i][j]);
        sel ^= 1;
    }
    if (job.N) {
#pragma unroll
        for (int i = 0; i < 4; i++) {
#pragma unroll
            for (int j = 0; j < 4; j++) {
                const int mr = m0 + wm + i * 16 + quad * 4;
                const int nc = n0 + wn + j * 16 + l16;
                const float sc = (nc < job.qcols) ? job.qscale : 1.0f;
                const float bv = job.bias[nc];
#pragma unroll
                for (int r = 0; r < 4; r++) {
                    const float v = (acc[i][j][r] + bv) * sc;
                    job.out[(size_t)(mr + r) * job.N + nc] = __float2bfloat16(v);
                }
            }
        }
    } else {
#pragma unroll
        for (int i = 0; i < 4; i++) {
            const int mr = m0 + wm + i * 16 + quad * 4;
            float bias_r[4];
#pragma unroll
            for (int r = 0; r < 4; r++) bias_r[r] = job.bias[mr + r];
#pragma unroll
            for (int j = 0; j < 4; j++) {
                const int nc = n0 + wn + j * 16 + l16;
#pragma unroll
                for (int r = 0; r < 4; r++) {
                    const int d = mr + r;
                    const size_t idx = ((size_t)bb << 20) + ((size_t)(d >> 6) << 16) +
                                       (size_t)(d & 63) * 1024 + nc;
                    job.out[idx] = __float2bfloat16(acc[i][j][r] + bias_r[r]);
                }
            }
        }
    }
}

// ---------------------------------------------------------------------------
// Flash attention: LDS-staged K/V (GLDS, double-buffered, 1 barrier/tile),
// 128 q-rows per pass (2 groups/wave share each K/V fragment), XCD swizzle,
// no-max softmax. paired=1 (causal): block processes q-tiles (7-p, p)
// sequentially -> every block does exactly 18 tile-units (load balance;
// all blocks co-resident so balance == wall time). paired=0: one q-tile.
//   S^T = K @ Q^T (q = l16 per lane), O^T = V^T @ P^T, sum via ones-MFMA.
// ---------------------------------------------------------------------------
__global__ __launch_bounds__(256) void attn_kernel(
    const __hip_bfloat16* __restrict__ Qp, const __hip_bfloat16* __restrict__ Kp,
    const __hip_bfloat16* __restrict__ Vt, __hip_bfloat16* __restrict__ Ob,
    int T, int qRS, int kRS, int causal, int paired) {
    __shared__ __align__(16) __hip_bfloat16 Ks[2][64 * 64];
    __shared__ __align__(16) __hip_bfloat16 Vs[2][64 * 64];
    __shared__ __align__(16) __hip_bfloat16 Ps[4][16 * 64];
    const int tid = threadIdx.x, wave = tid >> 6, lane = tid & 63;
    const int quad = lane >> 4, l16 = lane & 15;
    const int gid = blockIdx.x;
    const int bh = (gid & 7) * 16 + ((gid >> 3) & 15);
    const int sid = gid >> 7;  // pair id (paired) or q-tile id
    const int b = bh & 7, h = bh >> 3;
    const int qstride = 8 * qRS, kstride = 8 * kRS;
    const int sw = l16 & 7;
    const int jk = wave * 2;
    const int lrow = lane >> 3;
    const int lch = (lane & 7) ^ (lrow & 7);
    const __hip_bfloat16* qbase = Qp + (size_t)b * qRS + h * 64;
    const __hip_bfloat16* kbase =
        Kp + (size_t)b * kRS + h * 64 + (size_t)(jk * 8 + lrow) * kstride + lch * 8;
    const __hip_bfloat16* vbase =
        Vt + ((size_t)(b * 16 + h) << 16) + (size_t)(jk * 8 + lrow) * 1024 + lch * 8;
    const size_t kinc = (size_t)64 * kstride;
    bf16x8 onesf;
#pragma unroll
    for (int i = 0; i < 8; i++) onesf[i] = (__bf16)1.0f;

    const int nrep = paired ? 2 : 1;
    for (int rep = 0; rep < nrep; rep++) {
        const int qt = paired ? (rep ? sid : 7 - sid) : sid;
        const int q0 = qt * 128;
        const int qg0 = q0 + wave * 16;
        const int qg1 = qg0 + 64;
        const int myq0 = qg0 + l16, myq1 = qg1 + l16;
        const bf16x8 qf00 = *(const bf16x8*)(qbase + (size_t)myq0 * qstride + quad * 8);
        const bf16x8 qf01 =
            *(const bf16x8*)(qbase + (size_t)myq0 * qstride + 32 + quad * 8);
        const bf16x8 qf10 = *(const bf16x8*)(qbase + (size_t)myq1 * qstride + quad * 8);
        const bf16x8 qf11 =
            *(const bf16x8*)(qbase + (size_t)myq1 * qstride + 32 + quad * 8);

        f32x4 o0[4] = {}, o1[4] = {};
        f32x4 ol0 = {}, ol1 = {};
        bf16x8 pf00, pf01, pf10, pf11;

        auto softmax = [&](f32x4* s, f32x4& ol, bf16x8& pf0, bf16x8& pf1, int qg,
                           int myq, int k0) {
            const bool nm = causal && (k0 + 63 > qg);
            if (nm) {
#pragma unroll
                for (int n = 0; n < 4; n++)
#pragma unroll
                    for (int r = 0; r < 4; r++)
                        if (k0 + n * 16 + quad * 4 + r > myq) s[n][r] = -1e30f;
            }
#pragma unroll
            for (int n = 0; n < 4; n++) {
                const float p0 = __builtin_amdgcn_exp2f(s[n][0]);
                const float p1 = __builtin_amdgcn_exp2f(s[n][1]);
                const float p2 = __builtin_amdgcn_exp2f(s[n][2]);
                const float p3 = __builtin_amdgcn_exp2f(s[n][3]);
                const __hip_bfloat162 pa = __float22bfloat162_rn(make_float2(p0, p1));
                const __hip_bfloat162 pb = __float22bfloat162_rn(make_float2(p2, p3));
                uint2 w;
                w.x = *(const unsigned int*)&pa;
                w.y = *(const unsigned int*)&pb;
                const int gcp = 2 * n + (quad >> 1);
                *(uint2*)(&Ps[wave][l16 * 64 + ((gcp ^ sw) << 3) + (quad & 1) * 4]) = w;
            }
            pf0 = *(const bf16x8*)(&Ps[wave][l16 * 64 + ((quad ^ sw) << 3)]);
            pf1 = *(const bf16x8*)(&Ps[wave][l16 * 64 + (((quad + 4) ^ sw) << 3)]);
            ol = MFMA16(onesf, pf0, ol);
            ol = MFMA16(onesf, pf1, ol);
        };

        const int kend = causal ? (q0 + 128) : T;
        if (rep) __syncthreads();  // all waves done with prior rep's LDS reads
        GLDS(kbase, &Ks[0][jk * 512]);
        GLDS(kbase + (size_t)8 * kstride, &Ks[0][jk * 512 + 512]);
        GLDS(vbase, &Vs[0][jk * 512]);
        GLDS(vbase + 8 * 1024, &Vs[0][jk * 512 + 512]);
        const __hip_bfloat16* kn0 = kbase + kinc;
        const __hip_bfloat16* kn1 = kbase + (size_t)8 * kstride + kinc;
        const __hip_bfloat16* vn0 = vbase + 64;
        const __hip_bfloat16* vn1 = vbase + 8 * 1024 + 64;
        int sel = 0;
        for (int k0 = 0; k0 < kend; k0 += 64) {
            __syncthreads();  // buf[sel] staged; reads of buf[sel^1] done
            if (k0 + 64 < kend) {
                GLDS(kn0, &Ks[sel ^ 1][jk * 512]);
                GLDS(kn1, &Ks[sel ^ 1][jk * 512 + 512]);
                GLDS(vn0, &Vs[sel ^ 1][jk * 512]);
                GLDS(vn1, &Vs[sel ^ 1][jk * 512 + 512]);
                kn0 += kinc; kn1 += kinc; vn0 += 64; vn1 += 64;
            }
            const bool act0 = !causal || (k0 <= qg0 + 15);
            f32x4 s0[4] = {}, s1[4] = {};
            {
                bf16x8 kf[4];
#pragma unroll
                for (int n = 0; n < 4; n++)
                    kf[n] = *(const bf16x8*)(&Ks[sel][(n * 16 + l16) * 64 +
                                                      ((quad ^ sw) << 3)]);
#pragma unroll
                for (int n = 0; n < 4; n++) {
                    if (act0) s0[n] = MFMA16(kf[n], qf00, s0[n]);
                    s1[n] = MFMA16(kf[n], qf10, s1[n]);
                }
#pragma unroll
                for (int n = 0; n < 4; n++)
                    kf[n] = *(const bf16x8*)(&Ks[sel][(n * 16 + l16) * 64 +
                                                      (((quad + 4) ^ sw) << 3)]);
#pragma unroll
                for (int n = 0; n < 4; n++) {
                    if (act0) s0[n] = MFMA16(kf[n], qf01, s0[n]);
                    s1[n] = MFMA16(kf[n], qf11, s1[n]);
                }
            }
            if (act0) softmax(s0, ol0, pf00, pf01, qg0, myq0, k0);
            softmax(s1, ol1, pf10, pf11, qg1, myq1, k0);
#pragma unroll
            for (int mm = 0; mm < 4; mm++) {
                const int vrow = (mm * 16 + l16) * 64;
                const bf16x8 vf0 = *(const bf16x8*)(&Vs[sel][vrow + ((quad ^ sw) << 3)]);
                const bf16x8 vf1 =
                    *(const bf16x8*)(&Vs[sel][vrow + (((quad + 4) ^ sw) << 3)]);
                if (act0) {
                    o0[mm] = MFMA16(vf0, pf00, o0[mm]);
                    o0[mm] = MFMA16(vf1, pf01, o0[mm]);
                }
                o1[mm] = MFMA16(vf0, pf10, o1[mm]);
                o1[mm] = MFMA16(vf1, pf11, o1[mm]);
            }
            sel ^= 1;
        }
        const float inv0 = 1.0f / ol0[0];
        const float inv1 = 1.0f / ol1[0];
        __hip_bfloat16* ob0 = Ob + (size_t)b * 1024 + h * 64 + (size_t)myq0 * 8192;
        __hip_bfloat16* ob1 = Ob + (size_t)b * 1024 + h * 64 + (size_t)myq1 * 8192;
#pragma unroll
        for (int mm = 0; mm < 4; mm++) {
            __align__(8) __hip_bfloat16 t0[4] = {
                __float2bfloat16(o0[mm][0] * inv0), __float2bfloat16(o0[mm][1] * inv0),
                __float2bfloat16(o0[mm][2] * inv0), __float2bfloat16(o0[mm][3] * inv0)};
            *(uint2*)(ob0 + mm * 16 + quad * 4) = *(const uint2*)t0;
            __align__(8) __hip_bfloat16 t1[4] = {
                __float2bfloat16(o1[mm][0] * inv1), __float2bfloat16(o1[mm][1] * inv1),
                __float2bfloat16(o1[mm][2] * inv1), __float2bfloat16(o1[mm][3] * inv1)};
            *(uint2*)(ob1 + mm * 16 + quad * 4) = *(const uint2*)t1;
        }
    }
}

// ---------------------------------------------------------------------------
// Fused residual + LayerNorm over D=1024, one WAVE per row (no LDS/barrier).
// ---------------------------------------------------------------------------
__global__ __launch_bounds__(256) void ln_res_kernel(
    const __hip_bfloat16* __restrict__ a, const float* __restrict__ resf,
    const __hip_bfloat16* __restrict__ resb, const float* __restrict__ g,
    const float* __restrict__ be, float* __restrict__ outf,
    __hip_bfloat16* __restrict__ outb) {
    const int tid = threadIdx.x, wave = tid >> 6, lane = tid & 63;
    const int row = blockIdx.x * 4 + wave;
    const size_t base = (size_t)row * 1024;
    float x[16];
#pragma unroll
    for (int c = 0; c < 4; c++) {
        const int off = c * 256 + lane * 4;
        const uint2 ar = *(const uint2*)(a + base + off);
        const __hip_bfloat16* ah = (const __hip_bfloat16*)&ar;
        if (resf) {
            const float4 rv = *(const float4*)(resf + base + off);
            x[c * 4 + 0] = __bfloat162float(ah[0]) + rv.x;
            x[c * 4 + 1] = __bfloat162float(ah[1]) + rv.y;
            x[c * 4 + 2] = __bfloat162float(ah[2]) + rv.z;
            x[c * 4 + 3] = __bfloat162float(ah[3]) + rv.w;
        } else {
            const uint2 br = *(const uint2*)(resb + base + off);
            const __hip_bfloat16* bhp = (const __hip_bfloat16*)&br;
#pragma unroll
            for (int k = 0; k < 4; k++)
                x[c * 4 + k] = __bfloat162float(ah[k]) + __bfloat162float(bhp[k]);
        }
    }
    float s = 0.f, ss = 0.f;
#pragma unroll
    for (int k = 0; k < 16; k++) {
        s += x[k];
        ss += x[k] * x[k];
    }
#pragma unroll
    for (int w = 32; w >= 1; w >>= 1) {
        s += __shfl_xor(s, w);
        ss += __shfl_xor(ss, w);
    }
    const float mean = s * (1.f / 1024.f);
    const float inv = rsqrtf(ss * (1.f / 1024.f) - mean * mean + 1e-5f);
#pragma unroll
    for (int c = 0; c < 4; c++) {
        const int off = c * 256 + lane * 4;
        const float4 gg = *(const float4*)(g + off);
        const float4 bb = *(const float4*)(be + off);
        float y[4];
        y[0] = (x[c * 4 + 0] - mean) * inv * gg.x + bb.x;
        y[1] = (x[c * 4 + 1] - mean) * inv * gg.y + bb.y;
        y[2] = (x[c * 4 + 2] - mean) * inv * gg.z + bb.z;
        y[3] = (x[c * 4 + 3] - mean) * inv * gg.w + bb.w;
        if (outf) *(float4*)(outf + base + off) = make_float4(y[0], y[1], y[2], y[3]);
        if (outb) {
            __align__(8) __hip_bfloat16 t[4] = {
                __float2bfloat16(y[0]), __float2bfloat16(y[1]),
                __float2bfloat16(y[2]), __float2bfloat16(y[3])};
            *(uint2*)(outb + base + off) = *(const uint2*)t;
        }
    }
}

// ---------------------------------------------------------------------------
extern "C" void kernel_launch(void* const* d_in, const int* in_sizes, int n_in,
                              void* d_out, int out_size, void* d_ws, size_t ws_size,
                              hipStream_t stream) {
    const float* enc = (const float*)d_in[0];
    const float* dec = (const float*)d_in[1];
    const float* Wq1 = (const float*)d_in[2];
    const float* bq1 = (const float*)d_in[3];
    const float* Wk1 = (const float*)d_in[4];
    const float* bk1 = (const float*)d_in[5];
    const float* Wv1 = (const float*)d_in[6];
    const float* bv1 = (const float*)d_in[7];
    const float* Wq2 = (const float*)d_in[8];
    const float* bq2 = (const float*)d_in[9];
    const float* Wk2 = (const float*)d_in[10];
    const float* bk2 = (const float*)d_in[11];
    const float* Wv2 = (const float*)d_in[12];
    const float* bv2 = (const float*)d_in[13];
    const float* Wl = (const float*)d_in[14];
    const float* bl = (const float*)d_in[15];
    const float* g1 = (const float*)d_in[16];
    const float* be1 = (const float*)d_in[17];
    const float* g2 = (const float*)d_in[18];
    const float* be2 = (const float*)d_in[19];
    const float* g3 = (const float*)d_in[20];
    const float* be3 = (const float*)d_in[21];
    float* outp = (float*)d_out;

    char* p = (char*)d_ws;
    auto alloc = [&](size_t n) {
        char* r = p;
        p += (n + 255) & ~(size_t)255;
        return r;
    };
    const size_t MD = (size_t)8192 * 1024;
    __hip_bfloat16* enc_b = (__hip_bfloat16*)alloc(MD * 2);
    __hip_bfloat16* dec_b = (__hip_bfloat16*)alloc(MD * 2);
    __hip_bfloat16* Wt = (__hip_bfloat16*)alloc((size_t)7 * 1024 * 1024 * 2);
    float* bcat = (float*)alloc(2048 * sizeof(float));
    __hip_bfloat16* qk = (__hip_bfloat16*)alloc(MD * 2 * 2);  // QK1 [8192][2048]
    __hip_bfloat16* k2b = (__hip_bfloat16*)alloc(MD * 2);     // K2 [8192][1024]
    __hip_bfloat16* qb = (__hip_bfloat16*)alloc(MD * 2);      // Q2; reused as z
    __hip_bfloat16* attnb = (__hip_bfloat16*)alloc(MD * 2);   // attn outputs
    __hip_bfloat16* Vtb = (__hip_bfloat16*)alloc(MD * 2);     // V^T planes (attn1)
    __hip_bfloat16* Vtb2 = (__hip_bfloat16*)alloc(MD * 2);    // V^T planes (attn2)
    __hip_bfloat16* xb = dec_b;  // dec_b dead after mega1
    __hip_bfloat16* yb = enc_b;  // enc_b dead after mega2

    const float QSC = 0.18033688f;  // (1/sqrt(64)) * log2(e): softmax in exp2 domain

    PtrW wptrs = {{Wq1, Wk1, Wv1, Wq2, Wk2, Wv2, Wl}};
    wt_transpose<<<dim3(32, 32, 7), dim3(32, 8), 0, stream>>>(wptrs, Wt);
    PtrC cp = {{enc, dec}, {enc_b, dec_b}};
    to_bf16<<<dim3(8192, 2), 256, 0, stream>>>(cp);
    Ptr2 bp = {{bq1, bk1}};
    bias_concat<<<2, 256, 0, stream>>>(bp, bcat);

    // --- mega1: QK1 + VT1 (attn1 operands, dependency-adjacent) ---
    {
        Jobs J;
        J.j[0] = {dec_b, Wt, bcat, qk, 1024, 2048, 64 * 16, 64, QSC, 1024};
        J.j[1] = {Wt + ((size_t)2 << 20), dec_b, bv1, Vtb, 8192, 0, 512, 8, 1.0f, 0};
        J.njobs = 2;
        gemm_multi<<<1536, 256, 0, stream>>>(J);
    }

    // --- self-attention (paired q-tiles: balanced 18 tile-units per block) ---
    attn_kernel<<<512, 256, 0, stream>>>(qk, qk + 1024, Vtb, attnb,
                                         1024, 2048, 2048, 1, 1);
    ln_res_kernel<<<2048, 256, 0, stream>>>(attnb, dec, nullptr, g1, be1, nullptr, xb);

    // --- mega2: Q2 + K2 + VT2 (attn2 operands, L2-warm right before attn2) ---
    {
        Jobs J;
        J.j[0] = {xb, Wt + ((size_t)3 << 20), bq2, qb, 1024, 1024, 64 * 8, 64, QSC, 1024};
        J.j[1] = {enc_b, Wt + ((size_t)4 << 20), bk2, k2b, 1024, 1024, 64 * 8, 64, 1.0f, 0};
        J.j[2] = {Wt + ((size_t)5 << 20), enc_b, bv2, Vtb2, 8192, 0, 512, 8, 1.0f, 0};
        J.njobs = 3;
        gemm_multi<<<1536, 256, 0, stream>>>(J);
    }

    // --- cross-attention (uniform work; single q-tile per block) ---
    attn_kernel<<<1024, 256, 0, stream>>>(qb, k2b, Vtb2, attnb, 1024, 1024, 1024, 0, 0);
    ln_res_kernel<<<2048, 256, 0, stream>>>(attnb, nullptr, xb, g2, be2, nullptr, yb);

    // --- position-wise linear ---
    {
        Jobs J;
        J.j[0] = {yb, Wt + ((size_t)6 << 20), bl, qb, 1024, 1024, 64 * 8, 64, 1.0f, 0};
        J.njobs = 1;
        gemm_multi<<<512, 256, 0, stream>>>(J);
    }
    ln_res_kernel<<<2048, 256, 0, stream>>>(qb, nullptr, yb, g3, be3, outp, nullptr);
}